// Round 2
// baseline (128.997 us; speedup 1.0000x reference)
//
#include <hip/hip_runtime.h>
#include <hip/hip_cooperative_groups.h>

namespace cg = cooperative_groups;

// Cox PH loss, N=8192 fp32.
// R4: single fused cooperative kernel. Lessons from R3: LDS staging LOST 3 us
// (occupancy 4->2 blocks/CU + 49 MB redundant staging reads + barrier). Global
// L2-resident scan with 16 waves'/CU worth of ILP was never latency-bound.
// This round: (a) IPB 8->16 (512 blocks) halves redundant L2 scan traffic
// 98->49 MB with no LDS cost; (b) fuse finalize via grid.sync() -> one launch
// instead of two (saves launch gap + fin kernel's L2-latency stall).
// Inner loop floor: 201M VALU lane-ops = 2.6 us; L2: 49 MB = 1.4 us.

#define COX_N 8192
#define TPB   256
#define IPB   16                // i's owned per block (register-blocked per thread)
#define NBLK  (COX_N / IPB)     // 512 blocks = 2/CU (grid-limited), 8 waves/CU
#define JPT   (COX_N / TPB)     // 32 j-iterations per thread
#define NWAVE (TPB / 64)        // 4 waves per block

__global__ __launch_bounds__(TPB, 2) void cox_all(const float* __restrict__ y,
                                                  const float* __restrict__ theta,
                                                  float* __restrict__ partial,
                                                  float* __restrict__ out) {
    const int t  = threadIdx.x;
    const int b  = blockIdx.x;
    const int i0 = b * IPB;

    __shared__ float s_red[IPB][NWAVE];

    const float2* __restrict__ y2 = (const float2*)y;  // (N,2) row-major

    // i-block survtimes: uniform addresses -> scalar-load'able, once per block.
    float st[IPB], acc[IPB];
#pragma unroll
    for (int r = 0; r < IPB; ++r) { st[r] = y2[i0 + r].x; acc[r] = 0.f; }

    // Scan all j from global (96 KB inputs, L2-resident). Thread t handles
    // j = t + k*TPB: coalesced 8B float2 + 4B theta loads. Each j feeds 16
    // independent cmp/sel/add chains (ILP >> load latency at 8 waves/CU).
#pragma unroll 4
    for (int k = 0; k < JPT; ++k) {
        const int    j  = t + k * TPB;
        const float2 yv = y2[j];                 // {survtime_j, censor_j}
        const float  e  = __expf(theta[j]);
#pragma unroll
        for (int r = 0; r < IPB; ++r)
            acc[r] += (yv.x >= st[r]) ? e : 0.f;
    }

    // Wave-level reduce each of the 16 accumulators, then cross-wave via LDS.
    const int lane = t & 63, wave = t >> 6;
#pragma unroll
    for (int r = 0; r < IPB; ++r) {
        float v = acc[r];
        for (int off = 32; off > 0; off >>= 1)
            v += __shfl_down(v, off, 64);
        if (lane == 0) s_red[r][wave] = v;
    }
    __syncthreads();

    // Wave 0: lanes 0..15 finish their i; reduce 16 terms; one store per block.
    if (wave == 0) {
        float term = 0.f;
        if (t < IPB) {
            float risk = 0.f;
#pragma unroll
            for (int w = 0; w < NWAVE; ++w) risk += s_red[t][w];
            const int   i      = i0 + t;
            const float censor = (y2[i].y != 0.f) ? 1.f : 0.f;
            term = (theta[i] - __logf(risk)) * censor;
        }
        term += __shfl_down(term, 8, 64);
        term += __shfl_down(term, 4, 64);
        term += __shfl_down(term, 2, 64);
        term += __shfl_down(term, 1, 64);
        if (t == 0) partial[b] = term;
    }

    __threadfence();          // device-scope: partial[] visible across XCDs
    cg::this_grid().sync();

    // Block 0 finalizes the 512 partials; everyone else exits.
    if (b == 0) {
        float v = partial[t] + partial[t + 256];
        for (int off = 32; off > 0; off >>= 1)
            v += __shfl_down(v, off, 64);
        __shared__ float red2[NWAVE];
        if ((t & 63) == 0) red2[t >> 6] = v;
        __syncthreads();
        if (t == 0) out[0] = -(red2[0] + red2[1] + red2[2] + red2[3]) / (float)COX_N;
    }
}

extern "C" void kernel_launch(void* const* d_in, const int* in_sizes, int n_in,
                              void* d_out, int out_size, void* d_ws, size_t ws_size,
                              hipStream_t stream) {
    const float* y     = (const float*)d_in[0];  // (N,2): [survtime, censor]
    const float* theta = (const float*)d_in[1];  // (N,1)
    float* part = (float*)d_ws;                  // NBLK floats = 2 KB scratch
    float* out  = (float*)d_out;

    void* args[] = {(void*)&y, (void*)&theta, (void*)&part, (void*)&out};
    hipLaunchCooperativeKernel((void*)cox_all, dim3(NBLK), dim3(TPB),
                               args, 0, stream);
}

// Round 3
// 66.144 us; speedup vs baseline: 1.9502x; 1.9502x over previous
//
#include <hip/hip_runtime.h>

// Cox PH loss, N=8192 fp32.
// R5: back to the proven R2 two-kernel structure (R3 LDS-staging: -3us loss,
// occupancy+staging traffic; R4 cooperative grid.sync: -64us loss, ~57us
// barrier spin across XCDs). Single change vs R2: IPB 8->16 (512 blocks,
// 2/CU, 8 waves/CU). Halves redundant L2 scan traffic (98->49 MB) and
// halves per-j overhead (268M->160M lane-ops). 16 independent acc chains
// per loaded j = ample ILP; 4-deep unroll keeps 8 loads in flight per wave.

#define COX_N 8192
#define TPB   256
#define IPB   16                // i's owned per block (register-blocked per thread)
#define NBLK  (COX_N / IPB)     // 512 blocks = 2/CU, 8 waves/CU
#define JPT   (COX_N / TPB)     // 32 j-iterations per thread
#define NWAVE (TPB / 64)        // 4 waves per block

__global__ __launch_bounds__(TPB, 2) void cox_main(const float* __restrict__ y,
                                                   const float* __restrict__ theta,
                                                   float* __restrict__ partial) {
    const int t  = threadIdx.x;
    const int b  = blockIdx.x;
    const int i0 = b * IPB;

    __shared__ float s_red[IPB][NWAVE];

    const float2* __restrict__ y2 = (const float2*)y;  // (N,2) row-major

    // i-block survtimes: wave-uniform addresses -> scalar loads, once per block.
    float st[IPB], acc[IPB];
#pragma unroll
    for (int r = 0; r < IPB; ++r) { st[r] = y2[i0 + r].x; acc[r] = 0.f; }

    // Scan all j from global (96 KB inputs, L2-resident). Thread t handles
    // j = t + k*TPB: coalesced 8B float2 + 4B theta loads. Each j feeds 16
    // independent cmp/sel/add chains.
#pragma unroll 4
    for (int k = 0; k < JPT; ++k) {
        const int    j  = t + k * TPB;
        const float2 yv = y2[j];                 // {survtime_j, censor_j}
        const float  e  = __expf(theta[j]);
#pragma unroll
        for (int r = 0; r < IPB; ++r)
            acc[r] += (yv.x >= st[r]) ? e : 0.f;
    }

    // Wave-level reduce each of the 16 accumulators, then cross-wave via LDS.
    const int lane = t & 63, wave = t >> 6;
#pragma unroll
    for (int r = 0; r < IPB; ++r) {
        float v = acc[r];
        for (int off = 32; off > 0; off >>= 1)
            v += __shfl_down(v, off, 64);
        if (lane == 0) s_red[r][wave] = v;
    }
    __syncthreads();

    // Wave 0: lanes 0..15 finish their i; reduce 16 terms; one store per block.
    if (wave == 0) {
        float term = 0.f;
        if (t < IPB) {
            float risk = 0.f;
#pragma unroll
            for (int w = 0; w < NWAVE; ++w) risk += s_red[t][w];
            const int   i      = i0 + t;
            const float censor = (y2[i].y != 0.f) ? 1.f : 0.f;
            term = (theta[i] - __logf(risk)) * censor;
        }
        term += __shfl_down(term, 8, 64);
        term += __shfl_down(term, 4, 64);
        term += __shfl_down(term, 2, 64);
        term += __shfl_down(term, 1, 64);
        if (t == 0) partial[b] = term;
    }
}

__global__ __launch_bounds__(TPB) void cox_fin(const float* __restrict__ partial,
                                               float* __restrict__ out) {
    const int t = threadIdx.x;
    float v = partial[t] + partial[t + 256];     // NBLK = 512
    for (int off = 32; off > 0; off >>= 1)
        v += __shfl_down(v, off, 64);
    __shared__ float red[NWAVE];
    if ((t & 63) == 0) red[t >> 6] = v;
    __syncthreads();
    if (t == 0) out[0] = -(red[0] + red[1] + red[2] + red[3]) / (float)COX_N;
}

extern "C" void kernel_launch(void* const* d_in, const int* in_sizes, int n_in,
                              void* d_out, int out_size, void* d_ws, size_t ws_size,
                              hipStream_t stream) {
    const float* y     = (const float*)d_in[0];  // (N,2): [survtime, censor]
    const float* theta = (const float*)d_in[1];  // (N,1)
    float* part = (float*)d_ws;                  // NBLK floats = 2 KB scratch
    float* out  = (float*)d_out;

    cox_main<<<dim3(NBLK), dim3(TPB), 0, stream>>>(y, theta, part);
    cox_fin<<<dim3(1), dim3(TPB), 0, stream>>>(part, out);
}

// Round 4
// 64.928 us; speedup vs baseline: 1.9868x; 1.0187x over previous
//
#include <hip/hip_runtime.h>

// Cox PH loss, N=8192 fp32.
// R6: lock-in of the empirically-best R2 structure. Session ledger:
//   R2 (this structure, unroll 4): 64.7 us  <- best
//   R3 LDS-staged scan table:      67.8 us  (occupancy 4->2 blk/CU + 49MB staging)
//   R4 cooperative fused kernel:  129.0 us  (grid.sync spin ~57us across XCDs)
//   R5 IPB=16, 512 blocks:         66.1 us  (TLP loss > traffic saving)
// Budget: fill 39.3us (harness ws re-poison, at HBM roofline) + ~15us harness
// gaps + main ~6us + fin ~2us. Only change vs R2: j-loop unroll 4->8 (more
// loads in flight per wave; VGPR stays well under the 128 limit for 4 blk/CU).

#define COX_N 8192
#define TPB   256
#define IPB   8                 // i's owned per block (register-blocked per thread)
#define NBLK  (COX_N / IPB)     // 1024 blocks = 4/CU, 16 waves/CU
#define JPT   (COX_N / TPB)     // 32 j-iterations per thread
#define NWAVE (TPB / 64)        // 4 waves per block

__global__ __launch_bounds__(TPB, 4) void cox_main(const float* __restrict__ y,
                                                   const float* __restrict__ theta,
                                                   float* __restrict__ partial) {
    const int t  = threadIdx.x;
    const int b  = blockIdx.x;
    const int i0 = b * IPB;

    __shared__ float s_st[IPB];
    __shared__ float s_red[IPB][NWAVE];

    if (t < IPB) s_st[t] = y[2 * (i0 + t)];
    __syncthreads();

    float st[IPB], acc[IPB];
#pragma unroll
    for (int r = 0; r < IPB; ++r) { st[r] = s_st[r]; acc[r] = 0.f; }

    // Scan all j; thread t handles j = t + k*TPB (coalesced). Each loaded j
    // updates 8 independent accumulator chains (ILP hides dep latency);
    // 16 waves/CU of TLP covers L2 latency (R5 showed TLP > traffic here).
#pragma unroll 8
    for (int k = 0; k < JPT; ++k) {
        const int   j   = t + k * TPB;
        const float stj = y[2 * j];
        const float e   = __expf(theta[j]);
#pragma unroll
        for (int r = 0; r < IPB; ++r)
            acc[r] += (stj >= st[r]) ? e : 0.f;
    }

    // Wave-level reduce each of the 8 accumulators, then cross-wave via LDS.
    const int lane = t & 63, wave = t >> 6;
#pragma unroll
    for (int r = 0; r < IPB; ++r) {
        float v = acc[r];
        for (int off = 32; off > 0; off >>= 1)
            v += __shfl_down(v, off, 64);
        if (lane == 0) s_red[r][wave] = v;
    }
    __syncthreads();

    // Wave 0: lanes 0..7 finish their i; reduce 8 terms; one store per block.
    if (wave == 0) {
        float term = 0.f;
        if (t < IPB) {
            float risk = 0.f;
#pragma unroll
            for (int w = 0; w < NWAVE; ++w) risk += s_red[t][w];
            const int   i      = i0 + t;
            const float censor = (y[2 * i + 1] != 0.f) ? 1.f : 0.f;
            term = (theta[i] - __logf(risk)) * censor;
        }
        term += __shfl_down(term, 4, 64);
        term += __shfl_down(term, 2, 64);
        term += __shfl_down(term, 1, 64);
        if (t == 0) partial[b] = term;
    }
}

__global__ __launch_bounds__(TPB) void cox_fin(const float* __restrict__ partial,
                                               float* __restrict__ out) {
    const int t = threadIdx.x;
    float v = partial[t] + partial[t + 256] + partial[t + 512] + partial[t + 768];
    for (int off = 32; off > 0; off >>= 1)
        v += __shfl_down(v, off, 64);
    __shared__ float red[NWAVE];
    if ((t & 63) == 0) red[t >> 6] = v;
    __syncthreads();
    if (t == 0) out[0] = -(red[0] + red[1] + red[2] + red[3]) / (float)COX_N;
}

extern "C" void kernel_launch(void* const* d_in, const int* in_sizes, int n_in,
                              void* d_out, int out_size, void* d_ws, size_t ws_size,
                              hipStream_t stream) {
    const float* y     = (const float*)d_in[0];  // (N,2): [survtime, censor]
    const float* theta = (const float*)d_in[1];  // (N,1)
    float* part = (float*)d_ws;                  // NBLK floats = 4 KB scratch
    float* out  = (float*)d_out;

    cox_main<<<dim3(NBLK), dim3(TPB), 0, stream>>>(y, theta, part);
    cox_fin<<<dim3(1), dim3(TPB), 0, stream>>>(part, out);
}